// Round 4
// baseline (626.532 us; speedup 1.0000x reference)
//
#include <hip/hip_runtime.h>
#include <cmath>

#define EMB_V 100000
#define BATCH 256
#define SUBS  10
#define BC    2560
#define TC    20
#define TS    50

using bf16x8 = __attribute__((ext_vector_type(8))) short;
using f32x4  = __attribute__((ext_vector_type(4))) float;

__device__ __forceinline__ unsigned short f2bf(float f) {
    unsigned int u = __float_as_uint(f);
    u += 0x7fff + ((u >> 16) & 1);   // RNE
    return (unsigned short)(u >> 16);
}
__device__ __forceinline__ float bf2f(unsigned short u) {
    return __uint_as_float(((unsigned int)u) << 16);
}
__device__ __forceinline__ float sigmoid_fast(float x) {
    return __builtin_amdgcn_rcpf(1.f + __expf(-x));
}
__device__ __forceinline__ float tanh_fast(float x) {
    float e = __expf(2.f * x);                       // inf-safe: 1 - 2/(e+1)
    return 1.f - 2.f * __builtin_amdgcn_rcpf(e + 1.f);
}
// async 16B global -> LDS DMA. dst must be wave-uniform; HW adds lane*16.
__device__ __forceinline__ void dma16(const void* g, void* l) {
    __builtin_amdgcn_global_load_lds((const __attribute__((address_space(1))) void*)g,
                                     (__attribute__((address_space(3))) void*)l, 16, 0, 0);
}

// ---- merged small prep: fcWT transpose, pack_whh x2, Wih bf16 conv x2 ----
__device__ __forceinline__ void pack_whh_dev(const float* __restrict__ W,
                                             unsigned short* __restrict__ P, int t) {
    if (t >= 48 * 8 * 64) return;
    int l = t & 63, kc = (t >> 6) & 7, nt = t >> 9;
    int g = nt % 3, cg = nt / 3;
    int n = g * 256 + cg * 16 + (l & 15);
    int k = kc * 32 + (l >> 4) * 8;
    const float* src = W + n * 256 + k;
    unsigned short* dst = P + (size_t)t * 8;
#pragma unroll
    for (int j = 0; j < 8; ++j) dst[j] = f2bf(src[j]);
}
__global__ __launch_bounds__(256) void prep_misc(
    const float* __restrict__ fc_W, float* __restrict__ fcWT,
    const float* __restrict__ Whh_c, unsigned short* __restrict__ packW_c,
    const float* __restrict__ Whh_s, unsigned short* __restrict__ packW_s,
    const float* __restrict__ Wih_c, unsigned short* __restrict__ wihb_c,
    const float* __restrict__ Wih_s, unsigned short* __restrict__ wihb_s)
{
    const int b = blockIdx.x, tid = threadIdx.x;
    if (b < 512) {                       // fcWT[c*256+r] = fc_W[r*512+c]
        int o = b * 256 + tid;
        int c = o >> 8, r = o & 255;
        fcWT[o] = fc_W[r * 512 + c];
    } else if (b < 608) {
        pack_whh_dev(Whh_c, packW_c, (b - 512) * 256 + tid);
    } else if (b < 704) {
        pack_whh_dev(Whh_s, packW_s, (b - 608) * 256 + tid);
    } else if (b < 896) {
        int i = (b - 704) * 256 + tid;   // 49152 float4's
        float4 v = ((const float4*)Wih_c)[i];
        ((ushort4*)wihb_c)[i] = make_ushort4(f2bf(v.x), f2bf(v.y), f2bf(v.z), f2bf(v.w));
    } else {
        int i = (b - 896) * 256 + tid;
        float4 v = ((const float4*)Wih_s)[i];
        ((ushort4*)wihb_s)[i] = make_ushort4(f2bf(v.x), f2bf(v.y), f2bf(v.z), f2bf(v.w));
    }
}

// fp32 -> bf16 (RNE), vectorized, grid-strided. n4 = n/4.
__global__ void f32_to_bf16(const float* __restrict__ in, unsigned short* __restrict__ out,
                            int n4) {
    for (int i = blockIdx.x * 256 + threadIdx.x; i < n4; i += gridDim.x * 256) {
        float4 v = ((const float4*)in)[i];
        ((ushort4*)out)[i] = make_ushort4(f2bf(v.x), f2bf(v.y), f2bf(v.z), f2bf(v.w));
    }
}

// Generic C[m][n] = sum_k A[m][k]*B[n][k], K=256, BM=BN=128, bf16 inputs.
// m97-style staging: global_load_lds width-16 direct to linear [128][64] LDS.
// GIT>0: C written to the scan-ready packed gi layout (see gru_scan_fused),
// GIT is the GRU sequence length (compile-time -> magic-mul division).
template <bool GATHER, bool OBF16, bool NGUARD, int GIT>
__global__ __launch_bounds__(256, 3) void gemm_abt(
    const unsigned short* __restrict__ A, const int* __restrict__ tok,
    const unsigned short* __restrict__ B, void* __restrict__ Cout,
    int N, int ldc)
{
    __shared__ unsigned short Asub[128 * 64];
    __shared__ unsigned short Bsub[128 * 64];
    const int tid = threadIdx.x;
    const int l = tid & 63, wave = tid >> 6;
    const int lm = l & 15, quad = l >> 4;
    const int wm = wave >> 1, wn = wave & 1;
    const int n0 = blockIdx.x * 128, m0 = blockIdx.y * 128;

    // per-thread source offsets (u16 elements) for the 4 DMA issues of each tile
    unsigned aofs[4], bofs[4];
#pragma unroll
    for (int i = 0; i < 4; ++i) {
        int c = tid + i * 256, row = c >> 3, cc = c & 7;
        aofs[i] = (GATHER ? (unsigned)tok[m0 + row] : (unsigned)(m0 + row)) * 256u + cc * 8u;
        unsigned brow = (unsigned)(n0 + row);
        if (NGUARD && brow >= (unsigned)N) brow = (unsigned)N - 1;  // valid dup row; cols skipped at write
        bofs[i] = brow * 256u + cc * 8u;
    }
    const int dstu = (tid & 192) * 8;    // wave-uniform chunk base (u16)

    f32x4 acc[4][4];
#pragma unroll
    for (int mi = 0; mi < 4; ++mi)
#pragma unroll
        for (int ni = 0; ni < 4; ++ni) acc[mi][ni] = (f32x4){0.f, 0.f, 0.f, 0.f};

    for (int kk = 0; kk < 4; ++kk) {
        const int k0 = kk * 64;
#pragma unroll
        for (int i = 0; i < 4; ++i)
            dma16(A + aofs[i] + k0, &Asub[dstu + i * 2048]);
#pragma unroll
        for (int i = 0; i < 4; ++i)
            dma16(B + bofs[i] + k0, &Bsub[dstu + i * 2048]);
        __syncthreads();   // vmcnt(0) drain -> DMA complete
#pragma unroll
        for (int kc = 0; kc < 2; ++kc) {
            bf16x8 af[4], bfv[4];
#pragma unroll
            for (int mi = 0; mi < 4; ++mi)
                af[mi] = *(const bf16x8*)&Asub[(wm * 64 + mi * 16 + lm) * 64 + kc * 32 + quad * 8];
#pragma unroll
            for (int ni = 0; ni < 4; ++ni)
                bfv[ni] = *(const bf16x8*)&Bsub[(wn * 64 + ni * 16 + lm) * 64 + kc * 32 + quad * 8];
#pragma unroll
            for (int mi = 0; mi < 4; ++mi)
#pragma unroll
                for (int ni = 0; ni < 4; ++ni)
                    acc[mi][ni] = __builtin_amdgcn_mfma_f32_16x16x32_bf16(
                        af[mi], bfv[ni], acc[mi][ni], 0, 0, 0);
        }
        __syncthreads();
    }
#pragma unroll
    for (int mi = 0; mi < 4; ++mi)
#pragma unroll
        for (int ni = 0; ni < 4; ++ni) {
            int col = n0 + wn * 64 + ni * 16 + lm;
            if (NGUARD && col >= N) continue;
#pragma unroll
            for (int i = 0; i < 4; ++i) {
                int row = m0 + wm * 64 + mi * 16 + quad * 4 + i;
                if (GIT > 0) {
                    // scatter into scan-ready gi layout:
                    // bc = row/T, t = row%T, R = bc>>4, r = bc&15
                    // tau = (hcol>>5)*64 + (r>>2)*16 + (hcol&15)
                    // addr = ((R*T+t)*512 + tau)*24 + (r&3)*6 + ((hcol>>4)&1)*3 + g
                    unsigned bc = (unsigned)row / (unsigned)GIT;
                    unsigned tt = (unsigned)row - bc * (unsigned)GIT;
                    unsigned Rr = bc >> 4, rr = bc & 15;
                    unsigned g = (unsigned)col >> 8, hcol = (unsigned)col & 255;
                    unsigned tau = (hcol >> 5) * 64 + (rr >> 2) * 16 + (hcol & 15);
                    size_t ad = ((size_t)(Rr * (unsigned)GIT + tt) * 512 + tau) * 24
                              + (rr & 3) * 6 + ((hcol >> 4) & 1) * 3 + g;
                    ((unsigned short*)Cout)[ad] = f2bf(acc[mi][ni][i]);
                } else if (OBF16) {
                    ((unsigned short*)Cout)[(size_t)row * ldc + col] = f2bf(acc[mi][ni][i]);
                } else {
                    ((float*)Cout)[(size_t)row * ldc + col] = acc[mi][ni][i];
                }
            }
        }
}

// Fused GRU scans (cat: blocks 0..159, T=20; short: 160..175, T=50).
// 512 thr = 8 waves, 16 rows/block. B-frags: 40 in regs (lb(512,1) -> 256 VGPR
// budget), 8 in LDS. gi pre-packed so each thread's 24 gate values per step are
// 48 contiguous bytes -> 3 coalesced dwordx4 global loads, prefetched at step
// top, consumed after MFMA (latency hidden, zero LDS, zero addr VALU).
// Gates in-lane from accumulators (gate-triple-interleaved W). h double-buffered
// bf16 in LDS; one raw s_barrier/step draining lgkm only.
__global__ __launch_bounds__(512, 1) void gru_scan_fused(
    const unsigned short* __restrict__ gi_c, const unsigned short* __restrict__ pW_c,
    const float* __restrict__ bih_c, const float* __restrict__ bhh_c,
    const int* __restrict__ len_c, const float* __restrict__ mask_c,
    float* __restrict__ out_c,
    const unsigned short* __restrict__ gi_s, const unsigned short* __restrict__ pW_s,
    const float* __restrict__ bih_s, const float* __restrict__ bhh_s,
    const int* __restrict__ len_s, const float* __restrict__ mask_s,
    float* __restrict__ out_s)
{
    __shared__ unsigned short h_lds[2][16][264];   // 16896 B
    __shared__ unsigned short b_lds[8 * 8 * 512];  // 65536 B (8 frags/wave)

    const bool is_cat = blockIdx.x < (BC / 16);
    const int  T      = is_cat ? TC : TS;
    const int  R      = is_cat ? blockIdx.x : blockIdx.x - BC / 16;
    const int  row0   = R * 16;
    const unsigned short* gi   = is_cat ? gi_c  : gi_s;
    const unsigned short* pW   = is_cat ? pW_c  : pW_s;
    const float*          bih  = is_cat ? bih_c : bih_s;
    const float*          bhh  = is_cat ? bhh_c : bhh_s;
    const int*            lenp = is_cat ? len_c : len_s;
    const float*          mask = is_cat ? mask_c : mask_s;
    float*                outp = is_cat ? out_c : out_s;

    const int tid  = threadIdx.x;
    const int l    = tid & 63, w = tid >> 6;
    const int lm   = l & 15,   quad = l >> 4;

    // zero both h buffers
    for (int i = tid; i < 2 * 16 * 264; i += 512) ((unsigned short*)h_lds)[i] = 0;

    // B frags: ti<5 -> regs (40); ti==5 -> LDS (8 per wave)
    bf16x8 breg[40];
#pragma unroll
    for (int ti = 0; ti < 6; ++ti)
#pragma unroll
        for (int kc = 0; kc < 8; ++kc) {
            bf16x8 v = *((const bf16x8*)pW + (size_t)((6 * w + ti) * 8 + kc) * 64 + l);
            if (ti < 5) breg[ti * 8 + kc] = v;
            else        *(bf16x8*)&b_lds[((w * 8 + kc) * 64 + l) * 8] = v;
        }

    // per-lane columns and bias constants
    const int c0 = 32 * w + lm, c1 = c0 + 16;
    const float cR0 = bih[c0] + bhh[c0],             cR1 = bih[c1] + bhh[c1];
    const float cZ0 = bih[256 + c0] + bhh[256 + c0], cZ1 = bih[256 + c1] + bhh[256 + c1];
    const float cNi0 = bih[512 + c0], cNi1 = bih[512 + c1];
    const float cNh0 = bhh[512 + c0], cNh1 = bhh[512 + c1];

    int len[4];
#pragma unroll
    for (int i = 0; i < 4; ++i) len[i] = lenp[row0 + quad * 4 + i];

    // packed gi pointer: thread's 24 u16 per step at ((R*T+t)*512 + tid)*24
    const unsigned short* gp = gi + ((size_t)R * T * 512 + tid) * 24;

    float hold0[4] = {0.f, 0.f, 0.f, 0.f};
    float hold1[4] = {0.f, 0.f, 0.f, 0.f};

    __syncthreads();

#define GIV(e) bf2f((unsigned short)((e) < 8 ? gv0[(e)] : ((e) < 16 ? gv1[(e) - 8] : gv2[(e) - 16])))

    for (int t = 0; t < T; ++t) {
        // gi prefetch: 3 coalesced 16B loads (consumed after MFMA phase)
        bf16x8 gv0 = *(const bf16x8*)gp;
        bf16x8 gv1 = *(const bf16x8*)(gp + 8);
        bf16x8 gv2 = *(const bf16x8*)(gp + 16);
        gp += 512 * 24;

        // gh = h @ WhhT, kc-outer (1 live A-frag), 6 independent acc chains
        const unsigned short (*hb)[264] = h_lds[t & 1];
        f32x4 acc[6];
#pragma unroll
        for (int ti = 0; ti < 6; ++ti) acc[ti] = (f32x4){0.f, 0.f, 0.f, 0.f};
#pragma unroll
        for (int kc = 0; kc < 8; ++kc) {
            bf16x8 a = *(const bf16x8*)&hb[lm][kc * 32 + quad * 8];
#pragma unroll
            for (int ti = 0; ti < 6; ++ti) {
                bf16x8 b = (ti < 5) ? breg[ti * 8 + kc]
                                    : *(const bf16x8*)&b_lds[((w * 8 + kc) * 64 + l) * 8];
                acc[ti] = __builtin_amdgcn_mfma_f32_16x16x32_bf16(a, b, acc[ti], 0, 0, 0);
            }
        }

        // gates in-lane: acc[0..2] = (r,z,n) for col c0; acc[3..5] for col c1
        unsigned short (*hw)[264] = h_lds[(t + 1) & 1];
#pragma unroll
        for (int i = 0; i < 4; ++i) {
            const int r = quad * 4 + i;
            {
                float rg = sigmoid_fast(GIV(i * 6 + 0) + acc[0][i] + cR0);
                float zg = sigmoid_fast(GIV(i * 6 + 1) + acc[1][i] + cZ0);
                float ng = tanh_fast(GIV(i * 6 + 2) + cNi0 + rg * (acc[2][i] + cNh0));
                float hn = zg * (hold0[i] - ng) + ng;
                hold0[i] = hn;
                hw[r][c0] = f2bf(hn);
                if (t == len[i])
                    outp[(size_t)(row0 + r) * 256 + c0] = hn * mask[(row0 + r) * T + t];
            }
            {
                float rg = sigmoid_fast(GIV(i * 6 + 3) + acc[3][i] + cR1);
                float zg = sigmoid_fast(GIV(i * 6 + 4) + acc[4][i] + cZ1);
                float ng = tanh_fast(GIV(i * 6 + 5) + cNi1 + rg * (acc[5][i] + cNh1));
                float hn = zg * (hold1[i] - ng) + ng;
                hold1[i] = hn;
                hw[r][c1] = f2bf(hn);
                if (t == len[i])
                    outp[(size_t)(row0 + r) * 256 + c1] = hn * mask[(row0 + r) * T + t];
            }
        }

        // one barrier/step: h writes visible (lgkm only; no LDS-DMA in loop)
        asm volatile("s_waitcnt lgkmcnt(0)" ::: "memory");
        __builtin_amdgcn_sched_barrier(0);
        __builtin_amdgcn_s_barrier();
        __builtin_amdgcn_sched_barrier(0);
    }
#undef GIV
}

// Per-batch attention + fc; writes fc_out as bf16; target into d_out tail.
__global__ __launch_bounds__(256) void attn_fc(
    const float* __restrict__ seq_cate, const float* __restrict__ out_short,
    const float* __restrict__ mask_seq, const float* __restrict__ fcWT,
    const float* __restrict__ fc_b, const int* __restrict__ target,
    unsigned short* __restrict__ fc_out, float* __restrict__ d_out)
{
    __shared__ float sc[SUBS][256];
    __shared__ float os[256];
    __shared__ float part[SUBS][256];
    __shared__ float mix[512];
    const int b = blockIdx.x, tid = threadIdx.x;

    os[tid] = out_short[b * 256 + tid];
    for (int s = 0; s < SUBS; ++s) sc[s][tid] = seq_cate[(size_t)(b * SUBS + s) * 256 + tid];
    __syncthreads();

    for (int s = 0; s < SUBS; ++s) part[s][tid] = sc[s][tid] * os[tid];
    __syncthreads();
    for (int off = 128; off >= 1; off >>= 1) {
        if (tid < off)
            for (int s = 0; s < SUBS; ++s) part[s][tid] += part[s][tid + off];
        __syncthreads();
    }

    float w[SUBS];
    float m = -1e30f;
    for (int s = 0; s < SUBS; ++s) m = fmaxf(m, part[s][0]);
    float sum = 0.f;
    for (int s = 0; s < SUBS; ++s) { w[s] = __expf(part[s][0] - m); sum += w[s]; }
    float tot = 0.f;
    for (int s = 0; s < SUBS; ++s) { w[s] = (w[s] / sum) * mask_seq[b * SUBS + s]; tot += w[s]; }
    float inv = 1.f / tot;

    float sumc = 0.f;
    for (int s = 0; s < SUBS; ++s) sumc += w[s] * inv * sc[s][tid];
    mix[tid] = sumc;
    mix[256 + tid] = os[tid];
    __syncthreads();

    float acc = fc_b[tid];
    for (int jj = 0; jj < 512; ++jj) acc = fmaf(mix[jj], fcWT[jj * 256 + tid], acc);
    fc_out[b * 256 + tid] = f2bf(acc);

    if (tid == 0) d_out[(size_t)BATCH * EMB_V + b] = (float)target[b];
}

extern "C" void kernel_launch(void* const* d_in, const int* in_sizes, int n_in,
                              void* d_out, int out_size, void* d_ws, size_t ws_size,
                              hipStream_t stream) {
    const int*   input_cate   = (const int*)d_in[0];
    const float* mask_cate    = (const float*)d_in[1];
    const float* mask_seq     = (const float*)d_in[2];
    const int*   subseqLen    = (const int*)d_in[5];
    const int*   input_batch  = (const int*)d_in[7];
    const float* mask_batch   = (const float*)d_in[8];
    const int*   seqLen_batch = (const int*)d_in[9];
    const int*   target       = (const int*)d_in[10];
    const float* emb          = (const float*)d_in[12];
    const float* Wih_c        = (const float*)d_in[13];
    const float* Whh_c        = (const float*)d_in[14];
    const float* bih_c        = (const float*)d_in[15];
    const float* bhh_c        = (const float*)d_in[16];
    const float* Wih_s        = (const float*)d_in[17];
    const float* Whh_s        = (const float*)d_in[18];
    const float* bih_s        = (const float*)d_in[19];
    const float* bhh_s        = (const float*)d_in[20];
    const float* fc_W         = (const float*)d_in[21];
    const float* fc_b         = (const float*)d_in[22];
    float* out = (float*)d_out;

    float* ws = (float*)d_ws;
    float*          fcWT      = ws;                              // 131072 f
    float*          out_short = ws + 131072;                     // 65536 f
    unsigned short* fc_outb   = (unsigned short*)(ws + 196608);  // 65536 us
    float*          seq_cate  = ws + 229376;                     // 655360 f
    unsigned short* packW_c   = (unsigned short*)(ws + 884736);  // 98304 f
    unsigned short* packW_s   = (unsigned short*)(ws + 983040);  // 98304 f
    unsigned short* wihb_c    = (unsigned short*)(ws + 1081344); // 98304 f
    unsigned short* wihb_s    = (unsigned short*)(ws + 1179648); // 98304 f
    unsigned short* embb      = (unsigned short*)(ws + 1277952); // 12800000 f
    unsigned short* gi_c      = (unsigned short*)(ws + 14077952);// 19660800 f
    unsigned short* gi_s      = (unsigned short*)(ws + 33738752);// 4915200 f

    prep_misc<<<1088, 256, 0, stream>>>(fc_W, fcWT, Whh_c, packW_c, Whh_s, packW_s,
                                        Wih_c, wihb_c, Wih_s, wihb_s);
    f32_to_bf16<<<2048, 256, 0, stream>>>(emb, embb, EMB_V * 256 / 4);

    // input-gate GEMMs: gi = emb[tok] @ Wih^T, written in scan-packed layout
    gemm_abt<true, true, false, TC><<<dim3(6, 400), 256, 0, stream>>>(
        embb, input_cate, wihb_c, gi_c, 768, 768);
    gemm_abt<true, true, false, TS><<<dim3(6, 100), 256, 0, stream>>>(
        embb, input_batch, wihb_s, gi_s, 768, 768);

    // fused recurrent scans: 160 cat blocks + 16 short blocks, 512 thr
    gru_scan_fused<<<BC / 16 + BATCH / 16, 512, 0, stream>>>(
        gi_c, packW_c, bih_c, bhh_c, subseqLen, mask_cate, seq_cate,
        gi_s, packW_s, bih_s, bhh_s, seqLen_batch, mask_batch, out_short);

    attn_fc<<<BATCH, 256, 0, stream>>>(
        seq_cate, out_short, mask_seq, fcWT, fc_b, target, fc_outb, out);

    // logits = fc_out @ emb^T  (bf16 in, fp32 out)
    gemm_abt<false, false, true, 0><<<dim3(782, 2), 256, 0, stream>>>(
        fc_outb, nullptr, embb, out, EMB_V, EMB_V);
}

// Round 5
// 433.519 us; speedup vs baseline: 1.4452x; 1.4452x over previous
//
#include <hip/hip_runtime.h>
#include <cmath>

#define EMB_V 100000
#define BATCH 256
#define SUBS  10
#define BC    2560
#define TC    20
#define TS    50

using bf16x8 = __attribute__((ext_vector_type(8))) short;
using f32x4  = __attribute__((ext_vector_type(4))) float;

__device__ __forceinline__ unsigned short f2bf(float f) {
    unsigned int u = __float_as_uint(f);
    u += 0x7fff + ((u >> 16) & 1);   // RNE
    return (unsigned short)(u >> 16);
}
__device__ __forceinline__ float bf2f(unsigned short u) {
    return __uint_as_float(((unsigned int)u) << 16);
}
__device__ __forceinline__ float bf_lo(unsigned u) { return __uint_as_float(u << 16); }
__device__ __forceinline__ float bf_hi(unsigned u) { return __uint_as_float(u & 0xffff0000u); }
__device__ __forceinline__ float sigmoid_fast(float x) {
    return __builtin_amdgcn_rcpf(1.f + __expf(-x));
}
__device__ __forceinline__ float tanh_fast(float x) {
    float e = __expf(2.f * x);                       // inf-safe: 1 - 2/(e+1)
    return 1.f - 2.f * __builtin_amdgcn_rcpf(e + 1.f);
}
// async 16B global -> LDS DMA. dst must be wave-uniform; HW adds lane*16.
__device__ __forceinline__ void dma16(const void* g, void* l) {
    __builtin_amdgcn_global_load_lds((const __attribute__((address_space(1))) void*)g,
                                     (__attribute__((address_space(3))) void*)l, 16, 0, 0);
}

// ---- merged small prep: fcWT transpose, pack_whh x2, Wih bf16 conv x2 ----
// Whh pack is GATE-TRIPLE-INTERLEAVED with EVEN/ODD column pairing:
// tile ntg = cg*3+g; MFMA B-col index (l&15) maps to h-column
//   col = 32*(cg>>1) + 2*(l&15) + (cg&1)
// so the wave's two col-tiles give each lane ADJACENT h-columns -> the scan
// loads gi as dwords (2 bf16/load) and writes h as u32.
__device__ __forceinline__ void pack_whh_dev(const float* __restrict__ W,
                                             unsigned short* __restrict__ P, int t) {
    if (t >= 48 * 8 * 64) return;
    int l = t & 63, kc = (t >> 6) & 7, nt = t >> 9;
    int g = nt % 3, cg = nt / 3;
    int n = g * 256 + (cg >> 1) * 32 + 2 * (l & 15) + (cg & 1);
    int k = kc * 32 + (l >> 4) * 8;
    const float* src = W + n * 256 + k;
    unsigned short* dst = P + (size_t)t * 8;
#pragma unroll
    for (int j = 0; j < 8; ++j) dst[j] = f2bf(src[j]);
}
__global__ __launch_bounds__(256) void prep_misc(
    const float* __restrict__ fc_W, float* __restrict__ fcWT,
    const float* __restrict__ Whh_c, unsigned short* __restrict__ packW_c,
    const float* __restrict__ Whh_s, unsigned short* __restrict__ packW_s,
    const float* __restrict__ Wih_c, unsigned short* __restrict__ wihb_c,
    const float* __restrict__ Wih_s, unsigned short* __restrict__ wihb_s)
{
    const int b = blockIdx.x, tid = threadIdx.x;
    if (b < 512) {                       // fcWT[c*256+r] = fc_W[r*512+c]
        int o = b * 256 + tid;
        int c = o >> 8, r = o & 255;
        fcWT[o] = fc_W[r * 512 + c];
    } else if (b < 608) {
        pack_whh_dev(Whh_c, packW_c, (b - 512) * 256 + tid);
    } else if (b < 704) {
        pack_whh_dev(Whh_s, packW_s, (b - 608) * 256 + tid);
    } else if (b < 896) {
        int i = (b - 704) * 256 + tid;   // 49152 float4's
        float4 v = ((const float4*)Wih_c)[i];
        ((ushort4*)wihb_c)[i] = make_ushort4(f2bf(v.x), f2bf(v.y), f2bf(v.z), f2bf(v.w));
    } else {
        int i = (b - 896) * 256 + tid;
        float4 v = ((const float4*)Wih_s)[i];
        ((ushort4*)wihb_s)[i] = make_ushort4(f2bf(v.x), f2bf(v.y), f2bf(v.z), f2bf(v.w));
    }
}

// fp32 -> bf16 (RNE), vectorized, grid-strided. n4 = n/4.
__global__ void f32_to_bf16(const float* __restrict__ in, unsigned short* __restrict__ out,
                            int n4) {
    for (int i = blockIdx.x * 256 + threadIdx.x; i < n4; i += gridDim.x * 256) {
        float4 v = ((const float4*)in)[i];
        ((ushort4*)out)[i] = make_ushort4(f2bf(v.x), f2bf(v.y), f2bf(v.z), f2bf(v.w));
    }
}

// Generic C[m][n] = sum_k A[m][k]*B[n][k], K=256, BM=BN=128, bf16 inputs.
// dma16 staging into linear [128][8 chunks] LDS with XOR chunk-swizzle:
// LDS[row][cc] holds global[row][cc ^ (row&7)] (source pre-swizzled, per-lane
// global addr is legal with global_load_lds). Frag reads use the same XOR ->
// 8-request/bank floor instead of 16-way conflict (rule 21 / T2 both-sides).
template <bool GATHER, bool OBF16, bool NGUARD>
__global__ __launch_bounds__(256, 3) void gemm_abt(
    const unsigned short* __restrict__ A, const int* __restrict__ tok,
    const unsigned short* __restrict__ B, void* __restrict__ Cout,
    int N, int ldc)
{
    __shared__ unsigned short Asub[128 * 64];
    __shared__ unsigned short Bsub[128 * 64];
    const int tid = threadIdx.x;
    const int l = tid & 63, wave = tid >> 6;
    const int lm = l & 15, quad = l >> 4;
    const int wm = wave >> 1, wn = wave & 1;
    const int n0 = blockIdx.x * 128, m0 = blockIdx.y * 128;

    // per-thread source offsets (u16 units), chunk-swizzled by row&7
    unsigned aofs[4], bofs[4];
#pragma unroll
    for (int i = 0; i < 4; ++i) {
        int c = tid + i * 256, row = c >> 3, cc = c & 7;
        int sw = cc ^ (row & 7);
        aofs[i] = (GATHER ? (unsigned)tok[m0 + row] : (unsigned)(m0 + row)) * 256u + sw * 8u;
        unsigned brow = (unsigned)(n0 + row);
        if (NGUARD && brow >= (unsigned)N) brow = (unsigned)N - 1;  // valid dup row; cols skipped at write
        bofs[i] = brow * 256u + sw * 8u;
    }
    const int dstu = (tid & 192) * 8;    // wave-uniform chunk base (u16)
    const int fsw = lm & 7;              // frag-row&7 (row = ..+16*mi+lm)

    f32x4 acc[4][4];
#pragma unroll
    for (int mi = 0; mi < 4; ++mi)
#pragma unroll
        for (int ni = 0; ni < 4; ++ni) acc[mi][ni] = (f32x4){0.f, 0.f, 0.f, 0.f};

    for (int kk = 0; kk < 4; ++kk) {
        const int k0 = kk * 64;
#pragma unroll
        for (int i = 0; i < 4; ++i)
            dma16(A + aofs[i] + k0, &Asub[dstu + i * 2048]);
#pragma unroll
        for (int i = 0; i < 4; ++i)
            dma16(B + bofs[i] + k0, &Bsub[dstu + i * 2048]);
        __syncthreads();   // vmcnt(0) drain -> DMA complete
#pragma unroll
        for (int kc = 0; kc < 2; ++kc) {
            const int ch = ((kc * 4 + quad) ^ fsw) * 8;   // swizzled chunk offset (u16)
            bf16x8 af[4], bfv[4];
#pragma unroll
            for (int mi = 0; mi < 4; ++mi)
                af[mi] = *(const bf16x8*)&Asub[(wm * 64 + mi * 16 + lm) * 64 + ch];
#pragma unroll
            for (int ni = 0; ni < 4; ++ni)
                bfv[ni] = *(const bf16x8*)&Bsub[(wn * 64 + ni * 16 + lm) * 64 + ch];
#pragma unroll
            for (int mi = 0; mi < 4; ++mi)
#pragma unroll
                for (int ni = 0; ni < 4; ++ni)
                    acc[mi][ni] = __builtin_amdgcn_mfma_f32_16x16x32_bf16(
                        af[mi], bfv[ni], acc[mi][ni], 0, 0, 0);
        }
        __syncthreads();
    }
#pragma unroll
    for (int mi = 0; mi < 4; ++mi)
#pragma unroll
        for (int ni = 0; ni < 4; ++ni) {
            int col = n0 + wn * 64 + ni * 16 + lm;
            if (NGUARD && col >= N) continue;
#pragma unroll
            for (int i = 0; i < 4; ++i) {
                int row = m0 + wm * 64 + mi * 16 + quad * 4 + i;
                if (OBF16)
                    ((unsigned short*)Cout)[(size_t)row * ldc + col] = f2bf(acc[mi][ni][i]);
                else
                    ((float*)Cout)[(size_t)row * ldc + col] = acc[mi][ni][i];
            }
        }
}

// Fused GRU scans (cat: blocks 0..159, T=20; short: 160..175, T=50).
// 512 thr = 8 waves, 16 rows/block. B-frags: 40 in regs (lb(512,1) -> 256 VGPR
// budget), 8 in LDS. Even/odd-paired Whh pack -> lane owns ADJACENT h-cols
// (c0p, c0p+1): gi loads are 12 dword loads/thread/step from the LINEAR gi
// (prefetched at step top, consumed after MFMA), h written as u32, out as
// float2. Gates in-lane from accumulators. h double-buffered bf16 in LDS;
// one raw s_barrier/step draining lgkm only.
__global__ __launch_bounds__(512, 1) void gru_scan_fused(
    const unsigned short* __restrict__ gi_c, const unsigned short* __restrict__ pW_c,
    const float* __restrict__ bih_c, const float* __restrict__ bhh_c,
    const int* __restrict__ len_c, const float* __restrict__ mask_c,
    float* __restrict__ out_c,
    const unsigned short* __restrict__ gi_s, const unsigned short* __restrict__ pW_s,
    const float* __restrict__ bih_s, const float* __restrict__ bhh_s,
    const int* __restrict__ len_s, const float* __restrict__ mask_s,
    float* __restrict__ out_s)
{
    __shared__ unsigned short h_lds[2][16][264];   // 16896 B
    __shared__ unsigned short b_lds[8 * 8 * 512];  // 65536 B (8 frags/wave)

    const bool is_cat = blockIdx.x < (BC / 16);
    const int  T      = is_cat ? TC : TS;
    const int  R      = is_cat ? blockIdx.x : blockIdx.x - BC / 16;
    const int  row0   = R * 16;
    const unsigned short* gi   = is_cat ? gi_c  : gi_s;
    const unsigned short* pW   = is_cat ? pW_c  : pW_s;
    const float*          bih  = is_cat ? bih_c : bih_s;
    const float*          bhh  = is_cat ? bhh_c : bhh_s;
    const int*            lenp = is_cat ? len_c : len_s;
    const float*          mask = is_cat ? mask_c : mask_s;
    float*                outp = is_cat ? out_c : out_s;

    const int tid  = threadIdx.x;
    const int l    = tid & 63, w = tid >> 6;
    const int lm   = l & 15,   quad = l >> 4;

    // zero both h buffers
    for (int i = tid; i < 2 * 16 * 264; i += 512) ((unsigned short*)h_lds)[i] = 0;

    // B frags: ti<5 -> regs (40); ti==5 -> LDS (8 per wave)
    bf16x8 breg[40];
#pragma unroll
    for (int ti = 0; ti < 6; ++ti)
#pragma unroll
        for (int kc = 0; kc < 8; ++kc) {
            bf16x8 v = *((const bf16x8*)pW + (size_t)((6 * w + ti) * 8 + kc) * 64 + l);
            if (ti < 5) breg[ti * 8 + kc] = v;
            else        *(bf16x8*)&b_lds[((w * 8 + kc) * 64 + l) * 8] = v;
        }

    // per-lane ADJACENT columns and bias constants
    const int c0p = 32 * w + 2 * lm;       // even col; odd partner is c0p+1
    const float cR0 = bih[c0p] + bhh[c0p],             cR1 = bih[c0p + 1] + bhh[c0p + 1];
    const float cZ0 = bih[256 + c0p] + bhh[256 + c0p], cZ1 = bih[257 + c0p] + bhh[257 + c0p];
    const float cNi0 = bih[512 + c0p], cNi1 = bih[513 + c0p];
    const float cNh0 = bhh[512 + c0p], cNh1 = bhh[513 + c0p];

    int len[4];
    const unsigned short* gpa[4];
#pragma unroll
    for (int i = 0; i < 4; ++i) {
        const int r = quad * 4 + i;
        len[i] = lenp[row0 + r];
        gpa[i] = gi + (size_t)(row0 + r) * T * 768 + c0p;   // pre-offset, dword-aligned
    }

    float hold0[4] = {0.f, 0.f, 0.f, 0.f};
    float hold1[4] = {0.f, 0.f, 0.f, 0.f};

    __syncthreads();

    for (int t = 0; t < T; ++t) {
        // gi prefetch: 12 dword loads (each = both cols of one gate, one row)
        unsigned gv[4][3];
#pragma unroll
        for (int i = 0; i < 4; ++i) {
            const unsigned short* p = gpa[i];
            gv[i][0] = *(const unsigned*)(p);
            gv[i][1] = *(const unsigned*)(p + 256);
            gv[i][2] = *(const unsigned*)(p + 512);
            gpa[i] = p + 768;
        }

        // gh = h @ WhhT, kc-outer (1 live A-frag), 6 independent acc chains
        const unsigned short (*hb)[264] = h_lds[t & 1];
        f32x4 acc[6];
#pragma unroll
        for (int ti = 0; ti < 6; ++ti) acc[ti] = (f32x4){0.f, 0.f, 0.f, 0.f};
#pragma unroll
        for (int kc = 0; kc < 8; ++kc) {
            bf16x8 a = *(const bf16x8*)&hb[lm][kc * 32 + quad * 8];
#pragma unroll
            for (int ti = 0; ti < 6; ++ti) {
                bf16x8 b = (ti < 5) ? breg[ti * 8 + kc]
                                    : *(const bf16x8*)&b_lds[((w * 8 + kc) * 64 + l) * 8];
                acc[ti] = __builtin_amdgcn_mfma_f32_16x16x32_bf16(a, b, acc[ti], 0, 0, 0);
            }
        }

        // gates in-lane: acc[0..2] = (r,z,n) for col c0p; acc[3..5] for c0p+1
        unsigned short (*hw)[264] = h_lds[(t + 1) & 1];
#pragma unroll
        for (int i = 0; i < 4; ++i) {
            const int r = quad * 4 + i;
            float rg0 = sigmoid_fast(bf_lo(gv[i][0]) + acc[0][i] + cR0);
            float rg1 = sigmoid_fast(bf_hi(gv[i][0]) + acc[3][i] + cR1);
            float zg0 = sigmoid_fast(bf_lo(gv[i][1]) + acc[1][i] + cZ0);
            float zg1 = sigmoid_fast(bf_hi(gv[i][1]) + acc[4][i] + cZ1);
            float ng0 = tanh_fast(bf_lo(gv[i][2]) + cNi0 + rg0 * (acc[2][i] + cNh0));
            float ng1 = tanh_fast(bf_hi(gv[i][2]) + cNi1 + rg1 * (acc[5][i] + cNh1));
            float hn0 = zg0 * (hold0[i] - ng0) + ng0;
            float hn1 = zg1 * (hold1[i] - ng1) + ng1;
            hold0[i] = hn0; hold1[i] = hn1;
            *(unsigned*)&hw[r][c0p] = (unsigned)f2bf(hn0) | ((unsigned)f2bf(hn1) << 16);
            if (t == len[i]) {
                float m = mask[(row0 + r) * T + t];
                *(float2*)&outp[(size_t)(row0 + r) * 256 + c0p] = make_float2(hn0 * m, hn1 * m);
            }
        }

        // one barrier/step: h writes visible (lgkm only; no vmem dependency)
        asm volatile("s_waitcnt lgkmcnt(0)" ::: "memory");
        __builtin_amdgcn_sched_barrier(0);
        __builtin_amdgcn_s_barrier();
        __builtin_amdgcn_sched_barrier(0);
    }
}

// Per-batch attention + fc; writes fc_out as bf16; target into d_out tail.
__global__ __launch_bounds__(256) void attn_fc(
    const float* __restrict__ seq_cate, const float* __restrict__ out_short,
    const float* __restrict__ mask_seq, const float* __restrict__ fcWT,
    const float* __restrict__ fc_b, const int* __restrict__ target,
    unsigned short* __restrict__ fc_out, float* __restrict__ d_out)
{
    __shared__ float sc[SUBS][256];
    __shared__ float os[256];
    __shared__ float part[SUBS][256];
    __shared__ float mix[512];
    const int b = blockIdx.x, tid = threadIdx.x;

    os[tid] = out_short[b * 256 + tid];
    for (int s = 0; s < SUBS; ++s) sc[s][tid] = seq_cate[(size_t)(b * SUBS + s) * 256 + tid];
    __syncthreads();

    for (int s = 0; s < SUBS; ++s) part[s][tid] = sc[s][tid] * os[tid];
    __syncthreads();
    for (int off = 128; off >= 1; off >>= 1) {
        if (tid < off)
            for (int s = 0; s < SUBS; ++s) part[s][tid] += part[s][tid + off];
        __syncthreads();
    }

    float w[SUBS];
    float m = -1e30f;
    for (int s = 0; s < SUBS; ++s) m = fmaxf(m, part[s][0]);
    float sum = 0.f;
    for (int s = 0; s < SUBS; ++s) { w[s] = __expf(part[s][0] - m); sum += w[s]; }
    float tot = 0.f;
    for (int s = 0; s < SUBS; ++s) { w[s] = (w[s] / sum) * mask_seq[b * SUBS + s]; tot += w[s]; }
    float inv = 1.f / tot;

    float sumc = 0.f;
    for (int s = 0; s < SUBS; ++s) sumc += w[s] * inv * sc[s][tid];
    mix[tid] = sumc;
    mix[256 + tid] = os[tid];
    __syncthreads();

    float acc = fc_b[tid];
    for (int jj = 0; jj < 512; ++jj) acc = fmaf(mix[jj], fcWT[jj * 256 + tid], acc);
    fc_out[b * 256 + tid] = f2bf(acc);

    if (tid == 0) d_out[(size_t)BATCH * EMB_V + b] = (float)target[b];
}

extern "C" void kernel_launch(void* const* d_in, const int* in_sizes, int n_in,
                              void* d_out, int out_size, void* d_ws, size_t ws_size,
                              hipStream_t stream) {
    const int*   input_cate   = (const int*)d_in[0];
    const float* mask_cate    = (const float*)d_in[1];
    const float* mask_seq     = (const float*)d_in[2];
    const int*   subseqLen    = (const int*)d_in[5];
    const int*   input_batch  = (const int*)d_in[7];
    const float* mask_batch   = (const float*)d_in[8];
    const int*   seqLen_batch = (const int*)d_in[9];
    const int*   target       = (const int*)d_in[10];
    const float* emb          = (const float*)d_in[12];
    const float* Wih_c        = (const float*)d_in[13];
    const float* Whh_c        = (const float*)d_in[14];
    const float* bih_c        = (const float*)d_in[15];
    const float* bhh_c        = (const float*)d_in[16];
    const float* Wih_s        = (const float*)d_in[17];
    const float* Whh_s        = (const float*)d_in[18];
    const float* bih_s        = (const float*)d_in[19];
    const float* bhh_s        = (const float*)d_in[20];
    const float* fc_W         = (const float*)d_in[21];
    const float* fc_b         = (const float*)d_in[22];
    float* out = (float*)d_out;

    float* ws = (float*)d_ws;
    float*          fcWT      = ws;                              // 131072 f
    float*          out_short = ws + 131072;                     // 65536 f
    unsigned short* fc_outb   = (unsigned short*)(ws + 196608);  // 65536 us
    float*          seq_cate  = ws + 229376;                     // 655360 f
    unsigned short* packW_c   = (unsigned short*)(ws + 884736);  // 98304 f
    unsigned short* packW_s   = (unsigned short*)(ws + 983040);  // 98304 f
    unsigned short* wihb_c    = (unsigned short*)(ws + 1081344); // 98304 f
    unsigned short* wihb_s    = (unsigned short*)(ws + 1179648); // 98304 f
    unsigned short* embb      = (unsigned short*)(ws + 1277952); // 12800000 f
    unsigned short* gi_c      = (unsigned short*)(ws + 14077952);// 19660800 f
    unsigned short* gi_s      = (unsigned short*)(ws + 33738752);// 4915200 f

    prep_misc<<<1088, 256, 0, stream>>>(fc_W, fcWT, Whh_c, packW_c, Whh_s, packW_s,
                                        Wih_c, wihb_c, Wih_s, wihb_s);
    f32_to_bf16<<<2048, 256, 0, stream>>>(emb, embb, EMB_V * 256 / 4);

    // input-gate GEMMs: gi = emb[tok] @ Wih^T  (bf16 in, linear bf16 out)
    gemm_abt<true, true, false><<<dim3(6, 400), 256, 0, stream>>>(
        embb, input_cate, wihb_c, gi_c, 768, 768);
    gemm_abt<true, true, false><<<dim3(6, 100), 256, 0, stream>>>(
        embb, input_batch, wihb_s, gi_s, 768, 768);

    // fused recurrent scans: 160 cat blocks + 16 short blocks, 512 thr
    gru_scan_fused<<<BC / 16 + BATCH / 16, 512, 0, stream>>>(
        gi_c, packW_c, bih_c, bhh_c, subseqLen, mask_cate, seq_cate,
        gi_s, packW_s, bih_s, bhh_s, seqLen_batch, mask_batch, out_short);

    attn_fc<<<BATCH, 256, 0, stream>>>(
        seq_cate, out_short, mask_seq, fcWT, fc_b, target, fc_outb, out);

    // logits = fc_out @ emb^T  (bf16 in, fp32 out)
    gemm_abt<false, false, true><<<dim3(782, 2), 256, 0, stream>>>(
        fc_outb, nullptr, embb, out, EMB_V, EMB_V);
}